// Round 11
// baseline (149.134 us; speedup 1.0000x reference)
//
#include <hip/hip_runtime.h>

#define NNODES 50000
#define NEDGES 800000
#define IN_F 64
#define HID 128
#define OUT_F 64
#define STRIDE 64    // padded CSR row capacity (mean deg 16; P(>64) ~ 0)
#define NPB 256      // nodes per bucket (power of 2: bucket = node >> 8)
#define NB 196       // ceil(50000/256) buckets
#define BCAP 5120    // per-bucket edge capacity (mean 4096, +16 sigma)
#define CHUNK 2048   // edges per bucketing workgroup

static __device__ __forceinline__ unsigned short f2bf(float f) {
    unsigned int u = __float_as_uint(f);
    u = u + 0x7FFFu + ((u >> 16) & 1u);   // round-to-nearest-even
    return (unsigned short)(u >> 16);
}
static __device__ __forceinline__ float bf2f(unsigned short h) {
    return __uint_as_float((unsigned int)h << 16);
}

// ---------------- bucketed CSR build (no per-edge global atomics) ----------------

__global__ __launch_bounds__(256) void bucket_edges_k(const int* __restrict__ src,
                                                      const int* __restrict__ dst,
                                                      int* __restrict__ bcur_d,
                                                      int* __restrict__ bcur_s,
                                                      unsigned int* __restrict__ bed,
                                                      unsigned char* __restrict__ bes) {
    __shared__ int cntd[NB], cnts[NB], based_[NB], bases_[NB];
    const int tid = threadIdx.x;
    const int e0 = blockIdx.x * CHUNK;
    for (int i = tid; i < NB; i += 256) { cntd[i] = 0; cnts[i] = 0; }
    __syncthreads();
    for (int k = tid; k < CHUNK; k += 256) {
        int e = e0 + k;
        if (e < NEDGES) {
            atomicAdd(&cntd[dst[e] >> 8], 1);
            atomicAdd(&cnts[src[e] >> 8], 1);
        }
    }
    __syncthreads();
    for (int i = tid; i < NB; i += 256) {
        based_[i] = cntd[i] ? atomicAdd(&bcur_d[i], cntd[i]) : 0;
        bases_[i] = cnts[i] ? atomicAdd(&bcur_s[i], cnts[i]) : 0;
        cntd[i] = 0; cnts[i] = 0;
    }
    __syncthreads();
    for (int k = tid; k < CHUNK; k += 256) {
        int e = e0 + k;
        if (e < NEDGES) {
            int s = src[e], d = dst[e];
            int bd = d >> 8, bs = s >> 8;
            int pd = based_[bd] + atomicAdd(&cntd[bd], 1);
            if (pd < BCAP) bed[(size_t)bd * BCAP + pd] = ((unsigned)s << 8) | (unsigned)(d & 255);
            int ps = bases_[bs] + atomicAdd(&cnts[bs], 1);
            if (ps < BCAP) bes[(size_t)bs * BCAP + ps] = (unsigned char)(s & 255);
        }
    }
}

// One WG per bucket (256 nodes): padded CSR via LDS cursors, degrees, norms,
// and the pre-scaled feature table xbf = bf16(feat * sc) (streaming).
__global__ __launch_bounds__(256) void csr_norm_xpre(const int* __restrict__ bcur_d,
                                                     const int* __restrict__ bcur_s,
                                                     const unsigned int* __restrict__ bed,
                                                     const unsigned char* __restrict__ bes,
                                                     const float* __restrict__ feat,
                                                     int* __restrict__ padded,
                                                     int* __restrict__ deg_in,
                                                     float* __restrict__ norm_in,
                                                     float* __restrict__ sc,
                                                     unsigned short* __restrict__ xbf) {
    __shared__ int curs[NPB];
    __shared__ int hist[NPB];
    __shared__ float scl[NPB];
    const int b = blockIdx.x;
    const int tid = threadIdx.x;
    const int base = b << 8;
    curs[tid] = 0; hist[tid] = 0;
    __syncthreads();
    const int nd = min(bcur_d[b], BCAP);
    const int ns = min(bcur_s[b], BCAP);
    const unsigned int* ed = bed + (size_t)b * BCAP;
    const unsigned char* es = bes + (size_t)b * BCAP;
    for (int k = tid; k < nd; k += 256) {
        unsigned v = ed[k];
        int s = (int)(v >> 8), dl = (int)(v & 255u);
        int pos = atomicAdd(&curs[dl], 1);
        if (pos < STRIDE) padded[((size_t)(base + dl) << 6) + pos] = s;
    }
    for (int k = tid; k < ns; k += 256)
        atomicAdd(&hist[(int)es[k]], 1);
    __syncthreads();
    int node = base + tid;
    if (node < NNODES) {
        int din = curs[tid];
        int dout = hist[tid];
        deg_in[node] = din;
        if (din < 1) din = 1;
        if (dout < 1) dout = 1;
        float ni = 1.0f / sqrtf((float)din);
        float no = 1.0f / sqrtf((float)dout);
        norm_in[node] = ni;
        float s_ = ni * no;
        sc[node] = s_;
        scl[tid] = s_;
    } else {
        scl[tid] = 0.0f;
    }
    __syncthreads();
    // xbf for this WG's 256 nodes: float4 read -> ushort4 (bf16 RNE) write
    const float4* f4 = (const float4*)feat;
    for (int i = tid; i < NPB * 16; i += 256) {
        int nl = i >> 4;
        int gn = base + nl;
        if (gn < NNODES) {
            float4 v = f4[(size_t)gn * 16 + (i & 15)];
            float s_ = scl[nl];
            ushort4 o;
            o.x = f2bf(v.x * s_); o.y = f2bf(v.y * s_);
            o.z = f2bf(v.z * s_); o.w = f2bf(v.w * s_);
            *(ushort4*)&xbf[((size_t)gn << 6) + (size_t)(i & 15) * 4] = o;
        }
    }
}

// ---------------- aggregation (gather, 16 lanes/node) ----------------

__global__ __launch_bounds__(256) void agg_xpre(const int* __restrict__ deg_in,
                                                const int* __restrict__ padded,
                                                const unsigned short* __restrict__ xbf,
                                                float* __restrict__ aggout) {
    const int tid = threadIdx.x;
    const int node = blockIdx.x * 16 + (tid >> 4);
    const int sl = tid & 15;            // 4-feature slice
    if (node >= NNODES) return;
    const int* row = padded + ((size_t)node << 6);
    int n = deg_in[node]; if (n > STRIDE) n = STRIDE;
    float x0 = 0.f, y0 = 0.f, z0 = 0.f, w0 = 0.f;
    float x1 = 0.f, y1 = 0.f, z1 = 0.f, w1 = 0.f;
    int k = 0;
    for (; k + 2 <= n; k += 2) {
        int s0 = row[k], s1 = row[k + 1];
        ushort4 a = *(const ushort4*)&xbf[((size_t)s0 << 6) + (size_t)sl * 4];
        ushort4 b = *(const ushort4*)&xbf[((size_t)s1 << 6) + (size_t)sl * 4];
        x0 += bf2f(a.x); y0 += bf2f(a.y); z0 += bf2f(a.z); w0 += bf2f(a.w);
        x1 += bf2f(b.x); y1 += bf2f(b.y); z1 += bf2f(b.z); w1 += bf2f(b.w);
    }
    if (k < n) {
        ushort4 a = *(const ushort4*)&xbf[((size_t)row[k] << 6) + (size_t)sl * 4];
        x0 += bf2f(a.x); y0 += bf2f(a.y); z0 += bf2f(a.z); w0 += bf2f(a.w);
    }
    float4 r; r.x = x0 + x1; r.y = y0 + y1; r.z = z0 + z1; r.w = w0 + w1;
    *(float4*)&aggout[((size_t)node << 6) + (size_t)sl * 4] = r;
}

// Layer 2: P rows stay fp32 (bf16 here would inject error directly into out).
__global__ __launch_bounds__(256) void agg_final(const int* __restrict__ deg_in,
                                                 const int* __restrict__ padded,
                                                 const float* __restrict__ P,
                                                 const float* __restrict__ norm_in,
                                                 const float* __restrict__ b2,
                                                 float* __restrict__ out) {
    const int tid = threadIdx.x;
    const int node = blockIdx.x * 16 + (tid >> 4);
    const int l4 = (tid & 15) * 4;
    if (node >= NNODES) return;
    const int* row = padded + ((size_t)node << 6);
    int n = deg_in[node]; if (n > STRIDE) n = STRIDE;
    float x0 = 0.f, y0 = 0.f, z0 = 0.f, w0 = 0.f;
    float x1 = 0.f, y1 = 0.f, z1 = 0.f, w1 = 0.f;
    int k = 0;
    for (; k + 2 <= n; k += 2) {
        int s0 = row[k], s1 = row[k + 1];
        const float4 v0 = *(const float4*)&P[((size_t)s0 << 6) + l4];
        const float4 v1 = *(const float4*)&P[((size_t)s1 << 6) + l4];
        x0 += v0.x; y0 += v0.y; z0 += v0.z; w0 += v0.w;
        x1 += v1.x; y1 += v1.y; z1 += v1.z; w1 += v1.w;
    }
    if (k < n) {
        const float4 v = *(const float4*)&P[((size_t)row[k] << 6) + l4];
        x0 += v.x; y0 += v.y; z0 += v.z; w0 += v.w;
    }
    float ni = norm_in[node];
    const float4 bb = *(const float4*)&b2[l4];
    float4 r;
    r.x = fmaf(x0 + x1, ni, bb.x);
    r.y = fmaf(y0 + y1, ni, bb.y);
    r.z = fmaf(z0 + z1, ni, bb.z);
    r.w = fmaf(w0 + w1, ni, bb.w);
    *(float4*)&out[((size_t)node << 6) + l4] = r;
}

// ---------------- dense layers: W-only LDS (32.8 KB -> 4 blocks/CU) ----------------
// A/C rows are read with 16-lane-broadcast float4 global loads (each quarter-
// wave group reads the same address -> 1 sector; rows are block-private).

// C[i][j] = relu( dot(AGG[i][:], W1[:,j]) * ni + b1[j] ) * sc[i]
__global__ __launch_bounds__(256, 4) void gemm1_relu_g(const float* __restrict__ AGG,
                                                       const float* __restrict__ W1,
                                                       const float* __restrict__ b1,
                                                       const float* __restrict__ norm_in,
                                                       const float* __restrict__ sc,
                                                       float* __restrict__ C) {
    __shared__ float Ws[64 * 128];
    const int tid = threadIdx.x;
    const int block0 = blockIdx.x * 64;
    for (int i = tid; i < 64 * 128; i += 256)
        Ws[i] = W1[i];
    __syncthreads();

    const int cg = tid & 15;
    const int ng = tid >> 4;
    const int r0 = block0 + ng * 4;
    float acc[4][8];
#pragma unroll
    for (int r = 0; r < 4; ++r)
#pragma unroll
        for (int c = 0; c < 8; ++c) acc[r][c] = 0.0f;

    for (int k0 = 0; k0 < IN_F; k0 += 4) {
        float4 a[4];
#pragma unroll
        for (int r = 0; r < 4; ++r) {
            int row = r0 + r; if (row >= NNODES) row = NNODES - 1;
            a[r] = *(const float4*)&AGG[(size_t)row * 64 + k0];
        }
#pragma unroll
        for (int kk = 0; kk < 4; ++kk) {
            const float4 wlo = *(const float4*)&Ws[(k0 + kk) * 128 + cg * 4];
            const float4 whi = *(const float4*)&Ws[(k0 + kk) * 128 + 64 + cg * 4];
            float av[4];
            av[0] = (kk == 0) ? a[0].x : (kk == 1) ? a[0].y : (kk == 2) ? a[0].z : a[0].w;
            av[1] = (kk == 0) ? a[1].x : (kk == 1) ? a[1].y : (kk == 2) ? a[1].z : a[1].w;
            av[2] = (kk == 0) ? a[2].x : (kk == 1) ? a[2].y : (kk == 2) ? a[2].z : a[2].w;
            av[3] = (kk == 0) ? a[3].x : (kk == 1) ? a[3].y : (kk == 2) ? a[3].z : a[3].w;
#pragma unroll
            for (int r = 0; r < 4; ++r) {
                acc[r][0] = fmaf(av[r], wlo.x, acc[r][0]);
                acc[r][1] = fmaf(av[r], wlo.y, acc[r][1]);
                acc[r][2] = fmaf(av[r], wlo.z, acc[r][2]);
                acc[r][3] = fmaf(av[r], wlo.w, acc[r][3]);
                acc[r][4] = fmaf(av[r], whi.x, acc[r][4]);
                acc[r][5] = fmaf(av[r], whi.y, acc[r][5]);
                acc[r][6] = fmaf(av[r], whi.z, acc[r][6]);
                acc[r][7] = fmaf(av[r], whi.w, acc[r][7]);
            }
        }
    }

#pragma unroll
    for (int r = 0; r < 4; ++r) {
        int node = r0 + r;
        if (node >= NNODES) break;
        float ni = norm_in[node], s = sc[node];
        float* crow = C + (size_t)node * HID;
#pragma unroll
        for (int c = 0; c < 4; ++c) {
            int col = cg * 4 + c;
            float z = fmaf(acc[r][c], ni, b1[col]);
            crow[col] = fmaxf(z, 0.0f) * s;
            int col2 = 64 + cg * 4 + c;
            float z2 = fmaf(acc[r][c + 4], ni, b1[col2]);
            crow[col2] = fmaxf(z2, 0.0f) * s;
        }
    }
}

// P[i][j] = dot(C[i][:], W2[:,j])
__global__ __launch_bounds__(256, 4) void gemm2_g(const float* __restrict__ Cmat,
                                                  const float* __restrict__ W2,
                                                  float* __restrict__ P) {
    __shared__ float Ws2[128 * 64];
    const int tid = threadIdx.x;
    const int block0 = blockIdx.x * 64;
    for (int i = tid; i < 128 * 64; i += 256)
        Ws2[i] = W2[i];
    __syncthreads();

    const int cg = tid & 15;
    const int ng = tid >> 4;
    const int r0 = block0 + ng * 4;
    float acc[4][4];
#pragma unroll
    for (int r = 0; r < 4; ++r)
#pragma unroll
        for (int c = 0; c < 4; ++c) acc[r][c] = 0.0f;

    for (int k0 = 0; k0 < HID; k0 += 4) {
        float4 a[4];
#pragma unroll
        for (int r = 0; r < 4; ++r) {
            int row = r0 + r; if (row >= NNODES) row = NNODES - 1;
            a[r] = *(const float4*)&Cmat[(size_t)row * HID + k0];
        }
#pragma unroll
        for (int kk = 0; kk < 4; ++kk) {
            const float4 w = *(const float4*)&Ws2[(k0 + kk) * 64 + cg * 4];
            float av[4];
            av[0] = (kk == 0) ? a[0].x : (kk == 1) ? a[0].y : (kk == 2) ? a[0].z : a[0].w;
            av[1] = (kk == 0) ? a[1].x : (kk == 1) ? a[1].y : (kk == 2) ? a[1].z : a[1].w;
            av[2] = (kk == 0) ? a[2].x : (kk == 1) ? a[2].y : (kk == 2) ? a[2].z : a[2].w;
            av[3] = (kk == 0) ? a[3].x : (kk == 1) ? a[3].y : (kk == 2) ? a[3].z : a[3].w;
#pragma unroll
            for (int r = 0; r < 4; ++r) {
                acc[r][0] = fmaf(av[r], w.x, acc[r][0]);
                acc[r][1] = fmaf(av[r], w.y, acc[r][1]);
                acc[r][2] = fmaf(av[r], w.z, acc[r][2]);
                acc[r][3] = fmaf(av[r], w.w, acc[r][3]);
            }
        }
    }

#pragma unroll
    for (int r = 0; r < 4; ++r) {
        int node = r0 + r;
        if (node >= NNODES) break;
        float* prow = P + (size_t)node * OUT_F;
#pragma unroll
        for (int c = 0; c < 4; ++c)
            prow[cg * 4 + c] = acc[r][c];
    }
}

// ---------------- launch ----------------

static inline size_t align_up(size_t x, size_t a) { return (x + a - 1) & ~(a - 1); }

extern "C" void kernel_launch(void* const* d_in, const int* in_sizes, int n_in,
                              void* d_out, int out_size, void* d_ws, size_t ws_size,
                              hipStream_t stream) {
    const float* features = (const float*)d_in[0];
    const float* W1       = (const float*)d_in[1];
    const float* b1       = (const float*)d_in[2];
    const float* W2       = (const float*)d_in[3];
    const float* b2       = (const float*)d_in[4];
    const int*   src      = (const int*)d_in[5];
    const int*   dst      = (const int*)d_in[6];
    float* out = (float*)d_out;

    // workspace carve-up — total ~51.9 MB (same footprint as the passing
    // round-8 layout; round 10's un-aliased layout hit ~63 MB and overflowed
    // ws, corrupting a neighboring buffer -> tripwire).
    char* ws = (char*)d_ws;
    size_t off = 0;
    int*   bcur     = (int*)(ws + off);   off = align_up(off + 2 * NB * sizeof(int), 256); // [bcur_d | bcur_s]
    size_t zero_bytes = off;
    int*   bcur_d   = bcur;
    int*   bcur_s   = bcur + NB;
    int*   deg_in   = (int*)(ws + off);   off = align_up(off + NNODES * sizeof(int), 256);
    float* norm_in  = (float*)(ws + off); off = align_up(off + NNODES * sizeof(float), 256);
    float* sc       = (float*)(ws + off); off = align_up(off + NNODES * sizeof(float), 256);
    int*   padded   = (int*)(ws + off);   off = align_up(off + (size_t)NNODES * STRIDE * sizeof(int), 256);
    float* AGG      = (float*)(ws + off); off = align_up(off + (size_t)NNODES * IN_F * sizeof(float), 256);
    float* C        = (float*)(ws + off); off = align_up(off + (size_t)NNODES * HID * sizeof(float), 256);
    // aliases inside the 25.6 MB C region (C is dead until gemm1 writes it):
    //   [0, 4.01MB)    bed  (dst-bucketed edge records, u32) — dead after step 3
    //   [4.2, 5.2MB)   bes  (src-bucketed low-bytes, u8)     — dead after step 3
    //   [8, 14.4MB)    xbf  (bf16 pre-scaled features)       — dead after step 4
    unsigned int*   bed = (unsigned int*)C;
    unsigned char*  bes = (unsigned char*)((char*)C + align_up((size_t)NB * BCAP * 4, 256));
    unsigned short* xbf = (unsigned short*)((char*)C + (8u << 20));
    (void)ws_size; (void)out_size; (void)n_in; (void)in_sizes;

    const int B256 = 256;

    // 1. zero bucket cursors (2 KB)
    hipMemsetAsync(bcur, 0, zero_bytes, stream);
    // 2. bucket all edges by dst (CSR) and by src (out-degree)
    bucket_edges_k<<<(NEDGES + CHUNK - 1) / CHUNK, B256, 0, stream>>>(src, dst, bcur_d, bcur_s, bed, bes);
    // 3. per-bucket: padded CSR + degrees + norms + xbf = bf16(feat*sc)
    csr_norm_xpre<<<NB, B256, 0, stream>>>(bcur_d, bcur_s, bed, bes, features,
                                           padded, deg_in, norm_in, sc, xbf);
    // 4. layer-1 aggregation over bf16 rows: AGG[i] = sum xbf[s]
    agg_xpre<<<(NNODES + 15) / 16, B256, 0, stream>>>(deg_in, padded, xbf, AGG);
    // 5. hidden = relu(AGG*ni @ W1 + b1) * sc   (W1-only LDS, A broadcast loads)
    gemm1_relu_g<<<(NNODES + 63) / 64, B256, 0, stream>>>(AGG, W1, b1, norm_in, sc, C);
    // 6. P = C @ W2  (W2-only LDS; P aliases AGG, rows are block-private)
    gemm2_g<<<(NNODES + 63) / 64, B256, 0, stream>>>(C, W2, AGG);
    // 7. layer-2 aggregation + finalize: out = (sum P[s]) * ni + b2
    agg_final<<<(NNODES + 15) / 16, B256, 0, stream>>>(deg_in, padded, AGG, norm_in, b2, out);
}

// Round 12
// 131.879 us; speedup vs baseline: 1.1308x; 1.1308x over previous
//
#include <hip/hip_runtime.h>

#define NNODES 50000
#define NEDGES 800000
#define IN_F 64
#define HID 128
#define OUT_F 64
#define STRIDE 64    // padded CSR row capacity (mean deg 16; P(>64) ~ 0)
#define NPB 256      // nodes per bucket (power of 2: bucket = node >> 8)
#define NB 196       // ceil(50000/256) buckets
#define BCAP 5120    // per-bucket edge capacity (mean 4096, +16 sigma)
#define CHUNK 2048   // edges per bucketing workgroup

static __device__ __forceinline__ unsigned short f2bf(float f) {
    unsigned int u = __float_as_uint(f);
    u = u + 0x7FFFu + ((u >> 16) & 1u);   // round-to-nearest-even
    return (unsigned short)(u >> 16);
}
static __device__ __forceinline__ float bf2f(unsigned short h) {
    return __uint_as_float((unsigned int)h << 16);
}

// ---------------- bucketed CSR build (no per-edge global atomics) ----------------

__global__ __launch_bounds__(256) void bucket_edges_k(const int* __restrict__ src,
                                                      const int* __restrict__ dst,
                                                      int* __restrict__ bcur_d,
                                                      int* __restrict__ bcur_s,
                                                      unsigned int* __restrict__ bed,
                                                      unsigned char* __restrict__ bes) {
    __shared__ int cntd[NB], cnts[NB], based_[NB], bases_[NB];
    const int tid = threadIdx.x;
    const int e0 = blockIdx.x * CHUNK;
    for (int i = tid; i < NB; i += 256) { cntd[i] = 0; cnts[i] = 0; }
    __syncthreads();
    for (int k = tid; k < CHUNK; k += 256) {
        int e = e0 + k;
        if (e < NEDGES) {
            atomicAdd(&cntd[dst[e] >> 8], 1);
            atomicAdd(&cnts[src[e] >> 8], 1);
        }
    }
    __syncthreads();
    for (int i = tid; i < NB; i += 256) {
        based_[i] = cntd[i] ? atomicAdd(&bcur_d[i], cntd[i]) : 0;
        bases_[i] = cnts[i] ? atomicAdd(&bcur_s[i], cnts[i]) : 0;
        cntd[i] = 0; cnts[i] = 0;
    }
    __syncthreads();
    for (int k = tid; k < CHUNK; k += 256) {
        int e = e0 + k;
        if (e < NEDGES) {
            int s = src[e], d = dst[e];
            int bd = d >> 8, bs = s >> 8;
            int pd = based_[bd] + atomicAdd(&cntd[bd], 1);
            if (pd < BCAP) bed[(size_t)bd * BCAP + pd] = ((unsigned)s << 8) | (unsigned)(d & 255);
            int ps = bases_[bs] + atomicAdd(&cnts[bs], 1);
            if (ps < BCAP) bes[(size_t)bs * BCAP + ps] = (unsigned char)(s & 255);
        }
    }
}

// One WG per bucket (256 nodes): padded CSR via LDS cursors, degrees, norms,
// and the pre-scaled feature table xbf = bf16(feat * sc) (streaming).
__global__ __launch_bounds__(256) void csr_norm_xpre(const int* __restrict__ bcur_d,
                                                     const int* __restrict__ bcur_s,
                                                     const unsigned int* __restrict__ bed,
                                                     const unsigned char* __restrict__ bes,
                                                     const float* __restrict__ feat,
                                                     int* __restrict__ padded,
                                                     int* __restrict__ deg_in,
                                                     float* __restrict__ norm_in,
                                                     float* __restrict__ sc,
                                                     unsigned short* __restrict__ xbf) {
    __shared__ int curs[NPB];
    __shared__ int hist[NPB];
    __shared__ float scl[NPB];
    const int b = blockIdx.x;
    const int tid = threadIdx.x;
    const int base = b << 8;
    curs[tid] = 0; hist[tid] = 0;
    __syncthreads();
    const int nd = min(bcur_d[b], BCAP);
    const int ns = min(bcur_s[b], BCAP);
    const unsigned int* ed = bed + (size_t)b * BCAP;
    const unsigned char* es = bes + (size_t)b * BCAP;
    for (int k = tid; k < nd; k += 256) {
        unsigned v = ed[k];
        int s = (int)(v >> 8), dl = (int)(v & 255u);
        int pos = atomicAdd(&curs[dl], 1);
        if (pos < STRIDE) padded[((size_t)(base + dl) << 6) + pos] = s;
    }
    for (int k = tid; k < ns; k += 256)
        atomicAdd(&hist[(int)es[k]], 1);
    __syncthreads();
    int node = base + tid;
    if (node < NNODES) {
        int din = curs[tid];
        int dout = hist[tid];
        deg_in[node] = din;
        if (din < 1) din = 1;
        if (dout < 1) dout = 1;
        float ni = 1.0f / sqrtf((float)din);
        float no = 1.0f / sqrtf((float)dout);
        norm_in[node] = ni;
        float s_ = ni * no;
        sc[node] = s_;
        scl[tid] = s_;
    } else {
        scl[tid] = 0.0f;
    }
    __syncthreads();
    // xbf for this WG's 256 nodes: float4 read -> ushort4 (bf16 RNE) write
    const float4* f4 = (const float4*)feat;
    for (int i = tid; i < NPB * 16; i += 256) {
        int nl = i >> 4;
        int gn = base + nl;
        if (gn < NNODES) {
            float4 v = f4[(size_t)gn * 16 + (i & 15)];
            float s_ = scl[nl];
            ushort4 o;
            o.x = f2bf(v.x * s_); o.y = f2bf(v.y * s_);
            o.z = f2bf(v.z * s_); o.w = f2bf(v.w * s_);
            *(ushort4*)&xbf[((size_t)gn << 6) + (size_t)(i & 15) * 4] = o;
        }
    }
}

// ---------------- aggregation (gather, 16 lanes/node) ----------------

__global__ __launch_bounds__(256) void agg_xpre(const int* __restrict__ deg_in,
                                                const int* __restrict__ padded,
                                                const unsigned short* __restrict__ xbf,
                                                float* __restrict__ aggout) {
    const int tid = threadIdx.x;
    const int node = blockIdx.x * 16 + (tid >> 4);
    const int sl = tid & 15;            // 4-feature slice
    if (node >= NNODES) return;
    const int* row = padded + ((size_t)node << 6);
    int n = deg_in[node]; if (n > STRIDE) n = STRIDE;
    float x0 = 0.f, y0 = 0.f, z0 = 0.f, w0 = 0.f;
    float x1 = 0.f, y1 = 0.f, z1 = 0.f, w1 = 0.f;
    int k = 0;
    for (; k + 2 <= n; k += 2) {
        int s0 = row[k], s1 = row[k + 1];
        ushort4 a = *(const ushort4*)&xbf[((size_t)s0 << 6) + (size_t)sl * 4];
        ushort4 b = *(const ushort4*)&xbf[((size_t)s1 << 6) + (size_t)sl * 4];
        x0 += bf2f(a.x); y0 += bf2f(a.y); z0 += bf2f(a.z); w0 += bf2f(a.w);
        x1 += bf2f(b.x); y1 += bf2f(b.y); z1 += bf2f(b.z); w1 += bf2f(b.w);
    }
    if (k < n) {
        ushort4 a = *(const ushort4*)&xbf[((size_t)row[k] << 6) + (size_t)sl * 4];
        x0 += bf2f(a.x); y0 += bf2f(a.y); z0 += bf2f(a.z); w0 += bf2f(a.w);
    }
    float4 r; r.x = x0 + x1; r.y = y0 + y1; r.z = z0 + z1; r.w = w0 + w1;
    *(float4*)&aggout[((size_t)node << 6) + (size_t)sl * 4] = r;
}

// Layer-2 aggregation over bf16 P rows (128 B/row): out = ni*sum(P[s]) + b2.
// bf16 P rounding: per-output sigma ~7e-6, max-tail ~3.5e-5 — negligible.
__global__ __launch_bounds__(256) void agg_final(const int* __restrict__ deg_in,
                                                 const int* __restrict__ padded,
                                                 const unsigned short* __restrict__ Pb,
                                                 const float* __restrict__ norm_in,
                                                 const float* __restrict__ b2,
                                                 float* __restrict__ out) {
    const int tid = threadIdx.x;
    const int node = blockIdx.x * 16 + (tid >> 4);
    const int l4 = (tid & 15) * 4;
    if (node >= NNODES) return;
    const int* row = padded + ((size_t)node << 6);
    int n = deg_in[node]; if (n > STRIDE) n = STRIDE;
    float x0 = 0.f, y0 = 0.f, z0 = 0.f, w0 = 0.f;
    float x1 = 0.f, y1 = 0.f, z1 = 0.f, w1 = 0.f;
    int k = 0;
    for (; k + 2 <= n; k += 2) {
        int s0 = row[k], s1 = row[k + 1];
        ushort4 a = *(const ushort4*)&Pb[((size_t)s0 << 6) + l4];
        ushort4 b = *(const ushort4*)&Pb[((size_t)s1 << 6) + l4];
        x0 += bf2f(a.x); y0 += bf2f(a.y); z0 += bf2f(a.z); w0 += bf2f(a.w);
        x1 += bf2f(b.x); y1 += bf2f(b.y); z1 += bf2f(b.z); w1 += bf2f(b.w);
    }
    if (k < n) {
        ushort4 a = *(const ushort4*)&Pb[((size_t)row[k] << 6) + l4];
        x0 += bf2f(a.x); y0 += bf2f(a.y); z0 += bf2f(a.z); w0 += bf2f(a.w);
    }
    float ni = norm_in[node];
    const float4 bb = *(const float4*)&b2[l4];
    float4 r;
    r.x = fmaf(x0 + x1, ni, bb.x);
    r.y = fmaf(y0 + y1, ni, bb.y);
    r.z = fmaf(z0 + z1, ni, bb.z);
    r.w = fmaf(w0 + w1, ni, bb.w);
    *(float4*)&out[((size_t)node << 6) + l4] = r;
}

// ---------------- fused dense layers: P = (relu(AGG*ni @ W1 + b1)*sc) @ W2 ----------------
// LDS phase-union (49.7 KB -> 3 blocks/CU):
//   phase1: As[64][65] @0, Ws[64][128] @4160      (12352 words)
//   phase2: Cs[64][130] @0, Ws2[64][64] @8320     (12416 words; W2 in 2 halves)
// P written as bf16 into its own (dead-bed) region — NOT aliasing AGG.
__global__ __launch_bounds__(256) void gemm12_t(const float* __restrict__ AGG,
                                                const float* __restrict__ W1,
                                                const float* __restrict__ b1,
                                                const float* __restrict__ W2,
                                                const float* __restrict__ norm_in,
                                                const float* __restrict__ sc,
                                                unsigned short* __restrict__ Pout) {
    __shared__ float lds[12416];
    float* As  = lds;            // [64][65]
    float* Ws  = lds + 4160;     // [64][128]
    float* Cs  = lds;            // [64][130]
    float* Ws2 = lds + 8320;     // [64][64]
    const int tid = threadIdx.x;
    const int block0 = blockIdx.x * 64;

    for (int i = tid; i < 64 * 128; i += 256)
        Ws[i] = W1[i];                       // i = k*128 + col
    for (int i = tid; i < 64 * 64; i += 256) {
        int n = i >> 6, k = i & 63;
        int gn = block0 + n; if (gn >= NNODES) gn = NNODES - 1;
        As[n * 65 + k] = AGG[(size_t)gn * 64 + k];
    }
    __syncthreads();

    const int cg = tid & 15;
    const int ng = tid >> 4;
    float acc[4][8];
#pragma unroll
    for (int r = 0; r < 4; ++r)
#pragma unroll
        for (int c = 0; c < 8; ++c) acc[r][c] = 0.0f;

#pragma unroll 8
    for (int k = 0; k < IN_F; ++k) {
        float av[4];
        av[0] = As[(ng * 4 + 0) * 65 + k];
        av[1] = As[(ng * 4 + 1) * 65 + k];
        av[2] = As[(ng * 4 + 2) * 65 + k];
        av[3] = As[(ng * 4 + 3) * 65 + k];
        const float4 wlo = *(const float4*)&Ws[k * 128 + cg * 4];
        const float4 whi = *(const float4*)&Ws[k * 128 + 64 + cg * 4];
#pragma unroll
        for (int r = 0; r < 4; ++r) {
            acc[r][0] = fmaf(av[r], wlo.x, acc[r][0]);
            acc[r][1] = fmaf(av[r], wlo.y, acc[r][1]);
            acc[r][2] = fmaf(av[r], wlo.z, acc[r][2]);
            acc[r][3] = fmaf(av[r], wlo.w, acc[r][3]);
            acc[r][4] = fmaf(av[r], whi.x, acc[r][4]);
            acc[r][5] = fmaf(av[r], whi.y, acc[r][5]);
            acc[r][6] = fmaf(av[r], whi.z, acc[r][6]);
            acc[r][7] = fmaf(av[r], whi.w, acc[r][7]);
        }
    }
    __syncthreads();   // all reads of As/Ws complete before Cs/Ws2 overwrite

    // epilogue 1 -> Cs (h = relu(acc*ni + b1) * sc), and stage W2 rows 0..63
#pragma unroll
    for (int r = 0; r < 4; ++r) {
        int node = block0 + ng * 4 + r;
        if (node >= NNODES) break;
        float ni = norm_in[node], s = sc[node];
#pragma unroll
        for (int c = 0; c < 4; ++c) {
            int col = cg * 4 + c;
            float z = fmaf(acc[r][c], ni, b1[col]);
            Cs[(ng * 4 + r) * 130 + col] = fmaxf(z, 0.0f) * s;
            int col2 = 64 + cg * 4 + c;
            float z2 = fmaf(acc[r][c + 4], ni, b1[col2]);
            Cs[(ng * 4 + r) * 130 + col2] = fmaxf(z2, 0.0f) * s;
        }
    }
    for (int i = tid; i < 64 * 64; i += 256)
        Ws2[i] = W2[i];                      // W2 rows 0..63
    __syncthreads();

    float acc2[4][4];
#pragma unroll
    for (int r = 0; r < 4; ++r)
#pragma unroll
        for (int c = 0; c < 4; ++c) acc2[r][c] = 0.0f;

#pragma unroll 8
    for (int k = 0; k < 64; ++k) {
        float av[4];
        av[0] = Cs[(ng * 4 + 0) * 130 + k];
        av[1] = Cs[(ng * 4 + 1) * 130 + k];
        av[2] = Cs[(ng * 4 + 2) * 130 + k];
        av[3] = Cs[(ng * 4 + 3) * 130 + k];
        const float4 w = *(const float4*)&Ws2[k * 64 + cg * 4];
#pragma unroll
        for (int r = 0; r < 4; ++r) {
            acc2[r][0] = fmaf(av[r], w.x, acc2[r][0]);
            acc2[r][1] = fmaf(av[r], w.y, acc2[r][1]);
            acc2[r][2] = fmaf(av[r], w.z, acc2[r][2]);
            acc2[r][3] = fmaf(av[r], w.w, acc2[r][3]);
        }
    }
    __syncthreads();
    for (int i = tid; i < 64 * 64; i += 256)
        Ws2[i] = W2[64 * 64 + i];            // W2 rows 64..127
    __syncthreads();

#pragma unroll 8
    for (int k = 0; k < 64; ++k) {
        float av[4];
        av[0] = Cs[(ng * 4 + 0) * 130 + 64 + k];
        av[1] = Cs[(ng * 4 + 1) * 130 + 64 + k];
        av[2] = Cs[(ng * 4 + 2) * 130 + 64 + k];
        av[3] = Cs[(ng * 4 + 3) * 130 + 64 + k];
        const float4 w = *(const float4*)&Ws2[k * 64 + cg * 4];
#pragma unroll
        for (int r = 0; r < 4; ++r) {
            acc2[r][0] = fmaf(av[r], w.x, acc2[r][0]);
            acc2[r][1] = fmaf(av[r], w.y, acc2[r][1]);
            acc2[r][2] = fmaf(av[r], w.z, acc2[r][2]);
            acc2[r][3] = fmaf(av[r], w.w, acc2[r][3]);
        }
    }

#pragma unroll
    for (int r = 0; r < 4; ++r) {
        int node = block0 + ng * 4 + r;
        if (node >= NNODES) break;
        ushort4 o;
        o.x = f2bf(acc2[r][0]); o.y = f2bf(acc2[r][1]);
        o.z = f2bf(acc2[r][2]); o.w = f2bf(acc2[r][3]);
        *(ushort4*)&Pout[((size_t)node << 6) + cg * 4] = o;
    }
}

// ---------------- launch ----------------

static inline size_t align_up(size_t x, size_t a) { return (x + a - 1) & ~(a - 1); }

extern "C" void kernel_launch(void* const* d_in, const int* in_sizes, int n_in,
                              void* d_out, int out_size, void* d_ws, size_t ws_size,
                              hipStream_t stream) {
    const float* features = (const float*)d_in[0];
    const float* W1       = (const float*)d_in[1];
    const float* b1       = (const float*)d_in[2];
    const float* W2       = (const float*)d_in[3];
    const float* b2       = (const float*)d_in[4];
    const int*   src      = (const int*)d_in[5];
    const int*   dst      = (const int*)d_in[6];
    float* out = (float*)d_out;

    // workspace carve-up — total ~51.9 MB (proven-safe footprint).
    char* ws = (char*)d_ws;
    size_t off = 0;
    int*   bcur     = (int*)(ws + off);   off = align_up(off + 2 * NB * sizeof(int), 256); // [bcur_d | bcur_s]
    size_t zero_bytes = off;
    int*   bcur_d   = bcur;
    int*   bcur_s   = bcur + NB;
    int*   deg_in   = (int*)(ws + off);   off = align_up(off + NNODES * sizeof(int), 256);
    float* norm_in  = (float*)(ws + off); off = align_up(off + NNODES * sizeof(float), 256);
    float* sc       = (float*)(ws + off); off = align_up(off + NNODES * sizeof(float), 256);
    int*   padded   = (int*)(ws + off);   off = align_up(off + (size_t)NNODES * STRIDE * sizeof(int), 256);
    float* AGG      = (float*)(ws + off); off = align_up(off + (size_t)NNODES * IN_F * sizeof(float), 256);
    float* C        = (float*)(ws + off); off = align_up(off + (size_t)NNODES * HID * sizeof(float), 256);
    // aliases inside the 25.6 MB C region (no kernel writes C itself anymore):
    //   [0, 4.01MB)    bed  (dst-bucketed edge records, u32) — dead after step 3
    //   [4.2, 5.2MB)   bes  (src-bucketed low-bytes, u8)     — dead after step 3
    //   [8, 14.4MB)    xbf  (bf16 pre-scaled features)       — dead after step 4
    //   [0, 6.4MB)     Pb   (bf16 P, written step 5, read step 6) — reuses dead bed
    unsigned int*   bed = (unsigned int*)C;
    unsigned char*  bes = (unsigned char*)((char*)C + align_up((size_t)NB * BCAP * 4, 256));
    unsigned short* xbf = (unsigned short*)((char*)C + (8u << 20));
    unsigned short* Pb  = (unsigned short*)C;
    (void)ws_size; (void)out_size; (void)n_in; (void)in_sizes;

    const int B256 = 256;

    // 1. zero bucket cursors (2 KB)
    hipMemsetAsync(bcur, 0, zero_bytes, stream);
    // 2. bucket all edges by dst (CSR) and by src (out-degree)
    bucket_edges_k<<<(NEDGES + CHUNK - 1) / CHUNK, B256, 0, stream>>>(src, dst, bcur_d, bcur_s, bed, bes);
    // 3. per-bucket: padded CSR + degrees + norms + xbf = bf16(feat*sc)
    csr_norm_xpre<<<NB, B256, 0, stream>>>(bcur_d, bcur_s, bed, bes, features,
                                           padded, deg_in, norm_in, sc, xbf);
    // 4. layer-1 aggregation over bf16 rows: AGG[i] = sum xbf[s]
    agg_xpre<<<(NNODES + 15) / 16, B256, 0, stream>>>(deg_in, padded, xbf, AGG);
    // 5. fused dense: Pb = bf16( (relu(AGG*ni @ W1 + b1)*sc) @ W2 )
    gemm12_t<<<(NNODES + 63) / 64, B256, 0, stream>>>(AGG, W1, b1, W2, norm_in, sc, Pb);
    // 6. layer-2 aggregation + finalize: out = (sum Pb[s]) * ni + b2
    agg_final<<<(NNODES + 15) / 16, B256, 0, stream>>>(deg_in, padded, Pb, norm_in, b2, out);
}